// Round 1
// baseline (55.248 us; speedup 1.0000x reference)
//
#include <hip/hip_runtime.h>

#define SIG_LEN 2048
#define BATCH 16
#define BLOCK 256
#define ELEMS 4   // outputs per thread; grid = 16*2048/(256*4) = 32 blocks

// exp(-t^4) for integer t: only 5 distinct fp32 values, |t|>=4 underflows to 0.
#define W0 1.0f
#define W1 0.36787944117144233f    // exp(-1)
#define W2 1.1253517471925912e-07f // exp(-16)
#define W3 6.639677199580735e-36f  // exp(-81)

__global__ __launch_bounds__(BLOCK) void ParametricInterpolation_kernel(
    const float* __restrict__ x,       // [B, N]
    const float* __restrict__ params,  // [B, 5]
    float* __restrict__ out)           // [out | curve_val], each [B, N]
{
    __shared__ float xrow[SIG_LEN];

    // 2 blocks per batch row (each block covers 1024 outputs = 256 thr * 4).
    const int b  = blockIdx.x >> 1;
    const int i0 = ((blockIdx.x & 1) << 10) + (threadIdx.x << 2);

    // Stage this batch-row of x into LDS: 2 coalesced float4 loads/thread.
    // (Staging redundancy now 2x per row instead of 8x.)
    const float4* xb4 = (const float4*)(x + b * SIG_LEN);
    float4* xr4 = (float4*)xrow;
#pragma unroll
    for (int v = 0; v < (SIG_LEN / 4) / BLOCK; ++v)  // 2 iterations
        xr4[v * BLOCK + threadIdx.x] = xb4[v * BLOCK + threadIdx.x];
    __syncthreads();

    // p = params / SCALER, fp32 divides (correctly rounded, matches np).
    // b is wave-uniform -> compiler emits scalar loads.
    const float p0 = params[b * 5 + 0] / 1e11f;
    const float p1 = params[b * 5 + 1] / 1e7f;
    const float p2 = params[b * 5 + 2] / 1e3f;
    const float p3 = params[b * 5 + 3];
    const float p4 = params[b * 5 + 4];

    float o[ELEMS], c[ELEMS];

#pragma unroll
    for (int e = 0; e < ELEMS; ++e) {
        const int i = i0 + e;

        // powers of i: exact in double, rounded to fp32 (== np's correctly-rounded i**k).
        const double id = (double)i;
        const float pw4 = (float)(id * id * id * id);
        const float pw3 = (float)(id * id * id);
        const float pw2 = (float)(i * i);            // exact in fp32
        const float pw1 = (float)i;

        float cv = fmaf(p0, pw4, 0.0f);
        cv = fmaf(p1, pw3, cv);
        cv = fmaf(p2, pw2, cv);
        cv = fmaf(p3, pw1, cv);
        cv = cv + p4;

        const float ci = rintf(cv);          // round half-to-even == np.round
        const float d  = cv - ci;            // exact (Sterbenz)

        const float rawpos = (float)i - ci;  // exact integer in fp32
        const float npos   = fminf(fmaxf(rawpos, 1.0f), 2047.0f);
        const int   m      = (int)npos;      // in [1, 2047]

        // t = npos - j is an exact integer => weights are compile-time constants.
        // w1(dj) = T[dj+4], w2(dj) = T[dj+5]  (w2 center shifted by +1).
        const float T[10] = {0.0f, W3, W2, W1, W0, W1, W2, W3, 0.0f, 0.0f};

        float n1 = 0.0f, den1 = 0.0f, n2 = 0.0f, den2 = 0.0f;
#pragma unroll
        for (int dj = -4; dj <= 4; ++dj) {
            const int  j  = m + dj;
            const bool ok = (j >= 0) && (j < SIG_LEN);
            const int  jc = min(max(j, 0), SIG_LEN - 1);
            const float xv = xrow[jc];
            const float w1 = ok ? T[dj + 4] : 0.0f;   // folds to immediates
            const float w2 = ok ? T[dj + 5] : 0.0f;
            n1 = fmaf(xv, w1, n1);  den1 += w1;
            n2 = fmaf(xv, w2, n2);  den2 += w2;
        }

        const float a1 = n1 / den1;
        const float a2 = n2 / den2;
        o[e] = a1 * (1.0f - d) + a2 * d;
        c[e] = cv;
    }

    // Vectorized 16B/lane stores, fully coalesced (i0 is 16B-aligned).
    *(float4*)(out + b * SIG_LEN + i0) = make_float4(o[0], o[1], o[2], o[3]);
    *(float4*)(out + BATCH * SIG_LEN + b * SIG_LEN + i0) =
        make_float4(c[0], c[1], c[2], c[3]);
}

extern "C" void kernel_launch(void* const* d_in, const int* in_sizes, int n_in,
                              void* d_out, int out_size, void* d_ws, size_t ws_size,
                              hipStream_t stream) {
    const float* x      = (const float*)d_in[0];   // [16, 2048]
    const float* params = (const float*)d_in[1];   // [16, 5]
    float* out          = (float*)d_out;           // 2 * 16 * 2048 floats

    const int grid = BATCH * SIG_LEN / (BLOCK * ELEMS);   // 32 blocks
    ParametricInterpolation_kernel<<<grid, BLOCK, 0, stream>>>(x, params, out);
}